// Round 10
// baseline (79.375 us; speedup 1.0000x reference)
//
#include <hip/hip_runtime.h>

#define NQ 10

typedef float f32x2 __attribute__((ext_vector_type(2)));
struct cplx2 { f32x2 x, y; };  // .x/.y = real/imag; f32x2 comps = wire-3 halves (bit3)

__device__ __forceinline__ f32x2 mk2(float a, float b){ f32x2 v; v.x=a; v.y=b; return v; }
__device__ __forceinline__ f32x2 csw2(f32x2 v){ return __builtin_shufflevector(v, v, 1, 0); }
__device__ __forceinline__ cplx2 cswc(cplx2 a){ cplx2 r; r.x=csw2(a.x); r.y=csw2(a.y); return r; }

// ===== cross-lane xor-exchange =====
// masks 1,2,8: single DPP; mask 4: 2x DPP + select; masks 16,32: DS shfl_xor
template<int M>
__device__ __forceinline__ float lxf(float v){
    if constexpr (M == 1 || M == 2 || M == 8) {
        constexpr int ctrl = (M == 1) ? 0xB1 : (M == 2) ? 0x4E : 0x128;
        return __int_as_float(__builtin_amdgcn_update_dpp(
            0, __float_as_int(v), ctrl, 0xF, 0xF, true));
    } else if constexpr (M == 4) {
        float up = __int_as_float(__builtin_amdgcn_update_dpp(
            0, __float_as_int(v), 0x104, 0xF, 0xF, true));  // row_shl:4
        float dn = __int_as_float(__builtin_amdgcn_update_dpp(
            0, __float_as_int(v), 0x114, 0xF, 0xF, true));  // row_shr:4
        return (threadIdx.x & 4) ? dn : up;
    } else {
        return __shfl_xor(v, M, 64);
    }
}
template<int M>
__device__ __forceinline__ f32x2 lx2(f32x2 v){
    f32x2 r; r.x = lxf<M>(v.x); r.y = lxf<M>(v.y); return r;
}
template<int M>
__device__ __forceinline__ cplx2 lxc(cplx2 a){
    cplx2 r; r.x = lx2<M>(a.x); r.y = lx2<M>(a.y); return r;
}

// ===== Rot gate, wire in reg bits (wires 0-2): full pair update =====
template<int M, int R>
__device__ __forceinline__ void rot_reg(cplx2 (&a)[8],
        float u00x,float u00y,float u01x,float u01y,
        float u10x,float u10y,float u11x,float u11y){
    if constexpr (R < 8) {
        if constexpr ((R & M) == 0) {
            cplx2 a0 = a[R], a1 = a[R|M];
            a[R].x   = u00x*a0.x - u00y*a0.y + u01x*a1.x - u01y*a1.y;
            a[R].y   = u00x*a0.y + u00y*a0.x + u01x*a1.y + u01y*a1.x;
            a[R|M].x = u10x*a0.x - u10y*a0.y + u11x*a1.x - u11y*a1.y;
            a[R|M].y = u10x*a0.y + u10y*a0.x + u11x*a1.y + u11y*a1.x;
        }
        rot_reg<M,R+1>(a, u00x,u00y,u01x,u01y,u10x,u10y,u11x,u11y);
    }
}

// ===== Rot gate on wire 3 (vector component): packed coeffs, comp-swap partner =====
// uax=(u00x,u11x) uay=(u00y,u11y) ubx=(u01x,u10x) uby=(u01y,u10y)
template<int R>
__device__ __forceinline__ void rot_comp(cplx2 (&a)[8], f32x2 uax, f32x2 uay, f32x2 ubx, f32x2 uby){
    if constexpr (R < 8) {
        cplx2 m = a[R], p = cswc(m);
        a[R].x = uax*m.x - uay*m.y + ubx*p.x - uby*p.y;
        a[R].y = uax*m.y + uay*m.x + ubx*p.y + uby*p.x;
        rot_comp<R+1>(a, uax,uay,ubx,uby);
    }
}

// ===== Rot gate, wire in lane bits (wires 4-9): coeffs pre-selected by caller =====
template<int LM, int R>
__device__ __forceinline__ void rot_lane(cplx2 (&a)[8],
        float uax,float uay,float ubx,float uby){
    if constexpr (R < 8) {
        cplx2 p = lxc<LM>(a[R]);
        cplx2 m = a[R];
        a[R].x = uax*m.x - uay*m.y + ubx*p.x - uby*p.y;
        a[R].y = uax*m.y + uay*m.x + ubx*p.y + uby*p.x;
        rot_lane<LM,R+1>(a, uax,uay,ubx,uby);
    }
}

// ===== CRX(pi/3): symmetric pair op  n = al*mine - i*be*partner =====

template<int MC, int MT, int R>
__device__ __forceinline__ void crx_rr(cplx2 (&a)[8], float cc, float ss){
    if constexpr (R < 8) {
        if constexpr ((R & MC) != 0 && (R & MT) == 0) {
            cplx2 a0 = a[R], a1 = a[R|MT];
            a[R].x    = cc*a0.x + ss*a1.y;  a[R].y    = cc*a0.y - ss*a1.x;
            a[R|MT].x = cc*a1.x + ss*a0.y;  a[R|MT].y = cc*a1.y - ss*a0.x;
        }
        crx_rr<MC,MT,R+1>(a, cc, ss);
    }
}

// control in reg bits, target = component (wire 3)
template<int MC, int R>
__device__ __forceinline__ void crx_rc(cplx2 (&a)[8], float cc, float ss){
    if constexpr (R < 8) {
        if constexpr ((R & MC) != 0) {
            cplx2 m = a[R], p = cswc(m);
            a[R].x = cc*m.x + ss*p.y;
            a[R].y = cc*m.y - ss*p.x;
        }
        crx_rc<MC,R+1>(a, cc, ss);
    }
}

// control = component (wire 3), target in lane bits: packed al=(1,cc), be=(0,ss)
template<int LM, int R>
__device__ __forceinline__ void crx_cl(cplx2 (&a)[8], f32x2 al, f32x2 be){
    if constexpr (R < 8) {
        cplx2 p = lxc<LM>(a[R]);
        cplx2 m = a[R];
        a[R].x = al*m.x + be*p.y;
        a[R].y = al*m.y - be*p.x;
        crx_cl<LM,R+1>(a, al, be);
    }
}

// control in lane bits, target in reg bits: scalar al/be pre-selected
template<int MT, int R>
__device__ __forceinline__ void crx_lr(cplx2 (&a)[8], float al, float be){
    if constexpr (R < 8) {
        if constexpr ((R & MT) == 0) {
            cplx2 a0 = a[R], a1 = a[R|MT];
            a[R].x    = al*a0.x + be*a1.y;  a[R].y    = al*a0.y - be*a1.x;
            a[R|MT].x = al*a1.x + be*a0.y;  a[R|MT].y = al*a1.y - be*a0.x;
        }
        crx_lr<MT,R+1>(a, al, be);
    }
}

// both wires in lane bits: scalar al/be pre-selected
template<int TLM, int R>
__device__ __forceinline__ void crx_ll(cplx2 (&a)[8], float al, float be){
    if constexpr (R < 8) {
        cplx2 p = lxc<TLM>(a[R]);
        cplx2 m = a[R];
        a[R].x = al*m.x + be*p.y;
        a[R].y = al*m.y - be*p.x;
        crx_ll<TLM,R+1>(a, al, be);
    }
}

// ===== JIT Rot gate (RZ(omega) elided; Rot -> RY(th)RZ(phi)) =====
// u00=(A,-B) u01=(-C,-D) u10=(C,-D) u11=(A,B)
template<int I>
__device__ __forceinline__ void do_rot(cplx2 (&amp)[8], int lane, const float* __restrict__ w){
    float phi = w[I*3 + 0], th = w[I*3 + 1];
    float ct, st, cp, sp;
    __sincosf(0.5f * th,  &st, &ct);
    __sincosf(0.5f * phi, &sp, &cp);
    float A = ct*cp, Bv = ct*sp, C = st*cp, D = st*sp;
    if constexpr (I < 3) {
        rot_reg<(1<<I),0>(amp, A,-Bv, -C,-D, C,-D, A,Bv);
    } else if constexpr (I == 3) {
        rot_comp<0>(amp, mk2(A,A), mk2(-Bv,Bv), mk2(-C,C), mk2(-D,-D));
    } else {
        constexpr int LM = 1 << (I - 4);
        const bool hi = (lane & LM) != 0;
        float uax = A,            uay = hi ? Bv : -Bv;  // hi?u11:u00
        float ubx = hi ? C : -C,  uby = -D;             // hi?u10:u01
        rot_lane<LM,0>(amp, uax,uay,ubx,uby);
    }
}

// ===== measurement: packed accumulators, CNOT cascade folded into parity masks =====
// x = (lane<<4)|(comp<<3)|r.  Families: SA(sign r.b2), SB(sign comp), SC(sign r.b0^r.b2),
// SD(sign r.b1 ^ comp).  Comp sign realized by combining .s0 +/- .s1 at the end.
template<int R>
__device__ __forceinline__ void accum4(const cplx2 (&a)[8], f32x2 &PA, f32x2 &PB, f32x2 &PC, f32x2 &PD){
    if constexpr (R < 8) {
        f32x2 p = a[R].x*a[R].x + a[R].y*a[R].y;
        PA += ((R>>2) & 1)       ? -p : p;
        PB += p;
        PC += ((R ^ (R>>2)) & 1) ? -p : p;
        PD += ((R>>1) & 1)       ? -p : p;
        accum4<R+1>(a, PA, PB, PC, PD);
    }
}

__device__ __forceinline__ float wave_sum(float v){
    v += lxf< 1>(v);
    v += lxf< 2>(v);
    v += lxf< 4>(v);
    v += lxf< 8>(v);
    v += lxf<16>(v);
    v += lxf<32>(v);
    return v;
}

// 64-point Walsh-Hadamard over lanes: output lane l = sum_j (-1)^{popcount(j&l)} x_j
__device__ __forceinline__ float wht64(float v, int lane){
    float p;
    p = lxf< 1>(v); v = (lane &  1) ? p - v : v + p;
    p = lxf< 2>(v); v = (lane &  2) ? p - v : v + p;
    p = lxf< 4>(v); v = (lane &  4) ? p - v : v + p;
    p = lxf< 8>(v); v = (lane &  8) ? p - v : v + p;
    p = lxf<16>(v); v = (lane & 16) ? p - v : v + p;
    p = lxf<32>(v); v = (lane & 32) ? p - v : v + p;
    return v;
}

__device__ __forceinline__ float fsgn(float v, unsigned s){
    return __uint_as_float(__float_as_uint(v) ^ s);
}
__device__ __forceinline__ unsigned parsgn(int lane, int m){
    return (unsigned)((__builtin_popcount(lane & m) & 1)) << 31;
}

// (256,4) == hard 64-VGPR regime (empirical: cap = 512/(2*arg)).  amp is now only
// 32 VGPRs (8 cplx2), so the working set fits under 64 -> 8 waves/SIMD, no spill.
__global__ __launch_bounds__(256, 4) void qsim_kernel(const float* __restrict__ inputs,
                                                      const float* __restrict__ weights,
                                                      float* __restrict__ out, int B){
    const int lane = threadIdx.x & 63;
    const int wave = __builtin_amdgcn_readfirstlane((int)((blockIdx.x * blockDim.x + threadIdx.x) >> 6));
    if (wave >= B) return;

    const float* ang = inputs + (size_t)wave * NQ;

    // ---- lane-qubit factor F (wires 4-9 <-> lane bits 0-5) ----
    float F = 1.f;
    {
        float s, c;
        __sincosf(0.5f * ang[4], &s, &c); F *= (lane &  1) ? s : c;
        __sincosf(0.5f * ang[5], &s, &c); F *= (lane &  2) ? s : c;
        __sincosf(0.5f * ang[6], &s, &c); F *= (lane &  4) ? s : c;
        __sincosf(0.5f * ang[7], &s, &c); F *= (lane &  8) ? s : c;
        __sincosf(0.5f * ang[8], &s, &c); F *= (lane & 16) ? s : c;
        __sincosf(0.5f * ang[9], &s, &c); F *= (lane & 32) ? s : c;
    }

    // ---- product state over reg wires 0-2 and comp wire 3 ----
    float c0,s0,c1,s1,c2,s2,c3,s3;
    __sincosf(0.5f * ang[0], &s0, &c0);
    __sincosf(0.5f * ang[1], &s1, &c1);
    __sincosf(0.5f * ang[2], &s2, &c2);
    __sincosf(0.5f * ang[3], &s3, &c3);

    float v2a = F * c0, v2b = F * s0;
    float v4[4] = { v2a*c1, v2b*c1, v2a*s1, v2b*s1 };
    float v8[8] = { v4[0]*c2, v4[1]*c2, v4[2]*c2, v4[3]*c2,
                    v4[0]*s2, v4[1]*s2, v4[2]*s2, v4[3]*s2 };

    cplx2 amp[8];
    #pragma unroll
    for (int r = 0; r < 8; ++r) {
        amp[r].x = mk2(v8[r] * c3, v8[r] * s3);
        amp[r].y = 0.f;
    }

    // ---- CRX(pi/3) over chain edges (EDGES order) ----
    // wire->home: 0,1,2 = reg bits 1,2,4 ; 3 = comp ; 4..9 = lane masks 1..32
    const float cc = 0.86602540378443864676f;  // cos(pi/6)
    const float ss = 0.5f;                     // sin(pi/6)
    crx_rr<1, 2, 0>(amp, cc, ss);                                    // (0,1) reg-reg
    crx_rr<2, 4, 0>(amp, cc, ss);                                    // (1,2) reg-reg
    crx_rc<4, 0>(amp, cc, ss);                                       // (2,3) reg-comp
    crx_cl<1, 0>(amp, mk2(1.f, cc), mk2(0.f, ss));                   // (3,4) comp-lane(DPP)
    { bool t = (lane &  1); crx_ll< 2,0>(amp, t?cc:1.f, t?ss:0.f); } // (4,5) DPP
    { bool t = (lane &  2); crx_ll< 4,0>(amp, t?cc:1.f, t?ss:0.f); } // (5,6) 2xDPP
    { bool t = (lane &  4); crx_ll< 8,0>(amp, t?cc:1.f, t?ss:0.f); } // (6,7) DPP
    { bool t = (lane &  8); crx_ll<16,0>(amp, t?cc:1.f, t?ss:0.f); } // (7,8) DS
    { bool t = (lane & 16); crx_ll<32,0>(amp, t?cc:1.f, t?ss:0.f); } // (8,9) DS
    { bool t = (lane & 32); crx_lr< 1,0>(amp, t?cc:1.f, t?ss:0.f); } // (9,0) no shuffle

    // ---- StronglyEntanglingLayers Rot gates (RZ(omega) elided) ----
    do_rot<0>(amp, lane, weights);
    do_rot<1>(amp, lane, weights);
    do_rot<2>(amp, lane, weights);
    do_rot<3>(amp, lane, weights);
    do_rot<4>(amp, lane, weights);
    do_rot<5>(amp, lane, weights);
    do_rot<6>(amp, lane, weights);
    do_rot<7>(amp, lane, weights);
    do_rot<8>(amp, lane, weights);
    do_rot<9>(amp, lane, weights);

    // ---- measurement ----
    // o0:(SA, lane mask 21)  o1:(SB, 42)
    // SC family masks {0,1,5,21} -> o{2,4,6,8} ; SD family {0,2,10,42} -> o{3,5,7,9}
    f32x2 PA = 0.f, PB = 0.f, PC = 0.f, PD = 0.f;
    accum4<0>(amp, PA, PB, PC, PD);
    float SA = PA.x + PA.y;
    float SB = PB.x - PB.y;   // comp sign (bit3 in m1)
    float SC = PC.x + PC.y;
    float SD = PD.x - PD.y;   // comp sign (bit3 in m3)

    float r0  = wave_sum(fsgn(SA, parsgn(lane, 21)));
    float r1  = wave_sum(fsgn(SB, parsgn(lane, 42)));
    float wsc = wht64(SC, lane);
    float wsd = wht64(SD, lane);

    float* o = out + (size_t)wave * NQ;
    if (lane == 0)       { o[0] = r0; o[1] = r1; o[2] = wsc; o[3] = wsd; }
    else if (lane == 1)  o[4] = wsc;
    else if (lane == 5)  o[6] = wsc;
    else if (lane == 21) o[8] = wsc;
    if (lane == 2)       o[5] = wsd;
    else if (lane == 10) o[7] = wsd;
    else if (lane == 42) o[9] = wsd;
}

extern "C" void kernel_launch(void* const* d_in, const int* in_sizes, int n_in,
                              void* d_out, int out_size, void* d_ws, size_t ws_size,
                              hipStream_t stream) {
    const float* inputs  = (const float*)d_in[0];   // (B, 10) float32
    const float* weights = (const float*)d_in[1];   // (1, 10, 3) float32
    float* out = (float*)d_out;                     // (B, 10) float32
    const int B = in_sizes[0] / NQ;
    const int wavesPerBlock = 256 / 64;
    const int blocks = (B + wavesPerBlock - 1) / wavesPerBlock;
    qsim_kernel<<<blocks, 256, 0, stream>>>(inputs, weights, out, B);
}